// Round 3
// baseline (164.118 us; speedup 1.0000x reference)
//
#include <hip/hip_runtime.h>
#include <math.h>

#define TAU_INV 2.0f   // 1/0.5
#define EPS 1e-8f

// One 32-lane group per row (D=128 = 32 x float4). Grid-stride loop kept for
// safety but with nblk=ceil(N/8) each group handles exactly one row -> max
// TLP (occupancy cap 32 waves/CU; VGPR=20, LDS=512B are not limiting).
__global__ __launch_bounds__(256) void contrast_partial(
    const float* __restrict__ xr, const float* __restrict__ xp,
    const float* __restrict__ xn, float* __restrict__ partials, int N)
{
    const int lane   = threadIdx.x & 31;
    const int lgrp   = threadIdx.x >> 5;          // 0..7 within block
    const int stride = gridDim.x * 8;             // groups per grid pass

    float acc = 0.0f;
    for (int g = blockIdx.x * 8 + lgrp; g < N; g += stride) {
        const size_t base = (size_t)g * 128;
        const float4 r = ((const float4*)(xr + base))[lane];
        const float4 p = ((const float4*)(xp + base))[lane];
        const float4 n = ((const float4*)(xn + base))[lane];

        float s_rp = r.x*p.x + r.y*p.y + r.z*p.z + r.w*p.w;
        float s_rn = r.x*n.x + r.y*n.y + r.z*n.z + r.w*n.w;
        float s_rr = r.x*r.x + r.y*r.y + r.z*r.z + r.w*r.w;
        float s_pp = p.x*p.x + p.y*p.y + p.z*p.z + p.w*p.w;
        float s_nn = n.x*n.x + n.y*n.y + n.z*n.z + n.w*n.w;

        // Butterfly within the 32-lane group; xor masks < 32 stay inside
        // the half-wave.
        #pragma unroll
        for (int off = 16; off > 0; off >>= 1) {
            s_rp += __shfl_xor(s_rp, off);
            s_rn += __shfl_xor(s_rn, off);
            s_rr += __shfl_xor(s_rr, off);
            s_pp += __shfl_xor(s_pp, off);
            s_nn += __shfl_xor(s_nn, off);
        }

        const float nr  = sqrtf(s_rr);
        const float pos = expf(s_rp / (nr * sqrtf(s_pp)) * TAU_INV);
        const float neg = expf(s_rn / (nr * sqrtf(s_nn)) * TAU_INV);
        acc += pos / (neg + EPS);   // identical value on all 32 lanes
    }

    __shared__ float part[8];
    if (lane == 0) part[lgrp] = acc;
    __syncthreads();
    if (threadIdx.x == 0) {
        float t = 0.0f;
        #pragma unroll
        for (int i = 0; i < 8; ++i) t += part[i];
        partials[blockIdx.x] = t;   // plain store, unconditional, deterministic
    }
}

// Single block: reduce nblk partials (all freshly written), write -log(sum).
__global__ __launch_bounds__(1024) void contrast_final(
    const float* __restrict__ partials, float* __restrict__ out, int nblk)
{
    float s = 0.0f;
    for (int i = threadIdx.x; i < nblk; i += 1024)
        s += partials[i];

    #pragma unroll
    for (int off = 32; off > 0; off >>= 1)
        s += __shfl_xor(s, off);    // full wave64 butterfly

    __shared__ float w[16];
    if ((threadIdx.x & 63) == 0) w[threadIdx.x >> 6] = s;
    __syncthreads();
    if (threadIdx.x == 0) {
        float t = 0.0f;
        #pragma unroll
        for (int i = 0; i < 16; ++i) t += w[i];
        out[0] = -logf(t);
    }
}

extern "C" void kernel_launch(void* const* d_in, const int* in_sizes, int n_in,
                              void* d_out, int out_size, void* d_ws, size_t ws_size,
                              hipStream_t stream) {
    const float* xr = (const float*)d_in[0];
    const float* xp = (const float*)d_in[1];
    const float* xn = (const float*)d_in[2];
    float* out      = (float*)d_out;
    float* partials = (float*)d_ws;

    const int N = in_sizes[0] / 128;            // 100000

    // One row per 32-lane group: ceil(N/8) blocks. Clamp to ws capacity
    // (grid-stride loop in the kernel keeps any smaller grid correct).
    int nblk = (N + 7) / 8;                     // 12500 -> 50 KB of partials
    const int cap = (int)(ws_size / sizeof(float));
    if (nblk > cap) nblk = cap;

    contrast_partial<<<nblk, 256, 0, stream>>>(xr, xp, xn, partials, N);
    contrast_final<<<1, 1024, 0, stream>>>(partials, out, nblk);
}